// Round 11
// baseline (237.729 us; speedup 1.0000x reference)
//
#include <hip/hip_runtime.h>
#include <hip/hip_bf16.h>
#include <math.h>

// CausalSelfAttention: B=4, S=2048, D=1024, H=16, HD=64
// v13: attn re-banded for wave utilization. Block = (bh, jb8): ONE 256-row
//      q-band, 8 waves x 32 rows, all sharing the K/V staging. v11's hi/lo
//      band split left lo-band waves idling through 32% of all barrier
//      iterations (waves 4-7 needed only the first 2p+2 of 32-2p tiles).
//      Now wave w is active for 4*jb8+(w>>1)+1 of nt=4*jb8+4 tiles -> 92%
//      utilization, and total block-iterations drop 12800 -> 9216 (-28%).
//      praw<4 -> jb8=7-praw (long first), praw>=4 -> jb8=praw-4; co-resident
//      pairs (blk, blk+256) sum to nt=36. Inner loop unchanged from v11.
//      GEMMs unchanged from v12.

typedef __bf16 bf16;
typedef __bf16 bf16x8 __attribute__((ext_vector_type(8)));
typedef __bf16 bf16x4 __attribute__((ext_vector_type(4)));
typedef float f32x4 __attribute__((ext_vector_type(4)));

#define B_ 4
#define S_ 2048
#define D_ 1024
#define H_ 16
#define HD_ 64
#define QSCALE 0.1803368801f  /* 0.125 * log2(e) */

#if __has_builtin(__builtin_amdgcn_exp2f)
#define EXP2F(x) __builtin_amdgcn_exp2f(x)
#else
#define EXP2F(x) exp2f(x)
#endif
#if __has_builtin(__builtin_amdgcn_rcpf)
#define RCPF(x) __builtin_amdgcn_rcpf(x)
#else
#define RCPF(x) (1.0f / (x))
#endif

#define GLOAD_LDS16(gptr, lptr)                                              \
    __builtin_amdgcn_global_load_lds(                                        \
        (const __attribute__((address_space(1))) void*)(uintptr_t)(gptr),    \
        (__attribute__((address_space(3))) void*)(uintptr_t)(lptr), 16, 0, 0)

// ---------------- convert fp32 -> bf16 ----------------
__global__ void k_cvt(const float* __restrict__ in, bf16* __restrict__ out, int n) {
    int i = (blockIdx.x * 256 + threadIdx.x) * 4;
    if (i >= n) return;
    float4 v = *reinterpret_cast<const float4*>(in + i);
    bf16x4 o;
    o.x = (bf16)v.x; o.y = (bf16)v.y; o.z = (bf16)v.z; o.w = (bf16)v.w;
    *reinterpret_cast<bf16x4*>(out + i) = o;
}

// ---------------- transpose + convert: W[K][N] -> WT[N][K] bf16 ----------------
__global__ void k_transpose_cvt(const float* __restrict__ W, bf16* __restrict__ WT,
                                int K, int N) {
    __shared__ float t[32][33];
    int n0 = blockIdx.x * 32, k0 = blockIdx.y * 32;
    int tx = threadIdx.x & 31, ty = threadIdx.x >> 5;  // ty in 0..7
#pragma unroll
    for (int j = 0; j < 32; j += 8)
        t[ty + j][tx] = W[(size_t)(k0 + ty + j) * N + n0 + tx];
    __syncthreads();
#pragma unroll
    for (int j = 0; j < 32; j += 8)
        WT[(size_t)(n0 + ty + j) * K + k0 + tx] = (bf16)t[tx][ty + j];
}

// ---------------- bf16 MFMA GEMM v12: C = A[M][K] * BT[N][K]^T ---------------
// 128x128 tile, BK=64, double-buffered, counted vmcnt(4), raw barriers.
// 8 waves (512 thr), wave grid 2x4: wave w -> rows (w>>2)*64, cols (w&3)*32.
// [128][64] tiles, row-XOR swizzle (chunk c of row r holds global c^(r&7)).
// MODE 0: Q (prescaled) [bh][s][d], K [bh][s][d], V -> Vt [bh][d][s]
// MODE 1: fp32 out[M][N]
template <int MODE>
__global__ __launch_bounds__(512, 4) void k_gemm(
    const bf16* __restrict__ A, const bf16* __restrict__ BT,
    const float* __restrict__ bias,
    void* out0, void* out1, void* out2, int M, int N, int K) {
    __shared__ __align__(16) bf16 Asm[2][128][64];
    __shared__ __align__(16) bf16 Bsm[2][128][64];
    int mb = blockIdx.y * 128, nb = blockIdx.x * 128;
    int tid = threadIdx.x;
    int w = tid >> 6, lane = tid & 63, lo = lane & 15, qu = lane >> 4;
    int wm = (w >> 2) * 64, wn = (w & 3) * 32;
    int srow = lane >> 3, sch = lane & 7;
    int gch = (sch ^ srow) * 8;   // swizzled global chunk (bf16 elems)
    int r0 = w * 16;              // this wave's 16 staging rows per matrix

    f32x4 zero = {0.f, 0.f, 0.f, 0.f};
    f32x4 acc[4][2];
#pragma unroll
    for (int i = 0; i < 4; i++)
#pragma unroll
        for (int j = 0; j < 2; j++) acc[i][j] = zero;

    const int nt = K >> 6;  // 16

    auto stage = [&](int t, int buf) {
        int kb = t * 64;
#pragma unroll
        for (int g = 0; g < 2; g++) {
            int row = r0 + g * 8;  // 8-row group; lane covers row+srow
            GLOAD_LDS16(A + (size_t)(mb + row + srow) * K + kb + gch,
                        &Asm[buf][row][0]);
            GLOAD_LDS16(BT + (size_t)(nb + row + srow) * K + kb + gch,
                        &Bsm[buf][row][0]);
        }
    };

    stage(0, 0);

    for (int t = 0; t < nt; t++) {
        int cur = t & 1;
        if (t + 1 < nt) {
            stage(t + 1, cur ^ 1);
            // retire tile t's 4 loads; leave tile t+1's 4 in flight
            asm volatile("s_waitcnt vmcnt(4)" ::: "memory");
        } else {
            asm volatile("s_waitcnt vmcnt(0)" ::: "memory");
        }
        __builtin_amdgcn_s_barrier();
        asm volatile("" ::: "memory");
        bf16x8 af[4][2], bfr[2][2];
#pragma unroll
        for (int tt = 0; tt < 4; tt++)
#pragma unroll
            for (int ks = 0; ks < 2; ks++)
                af[tt][ks] = *reinterpret_cast<const bf16x8*>(
                    &Asm[cur][wm + tt * 16 + lo][((ks * 4 + qu) ^ (lo & 7)) * 8]);
#pragma unroll
        for (int j = 0; j < 2; j++)
#pragma unroll
            for (int ks = 0; ks < 2; ks++)
                bfr[j][ks] = *reinterpret_cast<const bf16x8*>(
                    &Bsm[cur][wn + j * 16 + lo][((ks * 4 + qu) ^ (lo & 7)) * 8]);
        __builtin_amdgcn_s_setprio(1);
#pragma unroll
        for (int i = 0; i < 4; i++)
#pragma unroll
            for (int j = 0; j < 2; j++) {
                acc[i][j] = __builtin_amdgcn_mfma_f32_16x16x32_bf16(
                    af[i][0], bfr[j][0], acc[i][j], 0, 0, 0);
                acc[i][j] = __builtin_amdgcn_mfma_f32_16x16x32_bf16(
                    af[i][1], bfr[j][1], acc[i][j], 0, 0, 0);
            }
        __builtin_amdgcn_s_setprio(0);
        asm volatile("" ::: "memory");
        __builtin_amdgcn_s_barrier();   // buf reads done before next prefetch
        asm volatile("" ::: "memory");
    }

#pragma unroll
    for (int i = 0; i < 4; i++) {
#pragma unroll
        for (int j = 0; j < 2; j++) {
            int col = nb + wn + j * 16 + lo;
            float bv = bias[col];
            float v4v[4];
#pragma unroll
            for (int r = 0; r < 4; r++) v4v[r] = acc[i][j][r] + bv;
            int row0 = mb + wm + i * 16 + qu * 4;
            if (MODE == 0) {
                int b = row0 >> 11, s0 = row0 & 2047;
                int which = col >> 10, rem = col & 1023;
                int h = rem >> 6, d = rem & 63;
                int bh = b * H_ + h;
                if (which == 2) {
                    // V: write transposed Vt[bh][d][s], 4 consecutive s packed
                    bf16x4 pk;
#pragma unroll
                    for (int r = 0; r < 4; r++) pk[r] = (bf16)v4v[r];
                    *reinterpret_cast<bf16x4*>(
                        (bf16*)out2 + ((size_t)bh * HD_ + d) * S_ + s0) = pk;
                } else {
                    bf16* dst = which == 0 ? (bf16*)out0 : (bf16*)out1;
                    float sc = which == 0 ? QSCALE : 1.0f;
#pragma unroll
                    for (int r = 0; r < 4; r++)
                        dst[((size_t)bh * S_ + s0 + r) * HD_ + d] = (bf16)(v4v[r] * sc);
                }
            } else {
#pragma unroll
                for (int r = 0; r < 4; r++)
                    ((float*)out0)[(size_t)(row0 + r) * N + col] = v4v[r];
            }
        }
    }
}

// ---------------- flash attention v13: one 256-row band per block ------------
// grid 512 blocks x 512 thr. Block (bh, jb8): q rows jb8*256 .. +255; wave w
// owns rows jb8*256 + w*32 .. +31. nt = 4*jb8+4 tiles of 64 keys; wave w is
// active for tiles t <= 4*jb8+(w>>1) -> 92% wave utilization. K/V staged to
// LDS (pre-swizzled source, linear dest), double-buffered, counted vmcnt(2).
// Swapped QK^T: st = mfma(K,Q) -> lane holds S^T[key=kc*16+qu*4+r][q=lo];
// P packed as bf16x4 -> 1 ds_write_b64 per (i,kc). Denominator l = P*ones MFMA.
__global__ __launch_bounds__(512, 4) void k_attn(
    const bf16* __restrict__ Q, const bf16* __restrict__ K,
    const bf16* __restrict__ Vt, bf16* __restrict__ Y) {
    __shared__ __align__(16) bf16 Ks[2][64][64];   // [buf][key][d]   (swizzled)
    __shared__ __align__(16) bf16 Vs[2][64][64];   // [buf][d][key]   (swizzled)
    __shared__ __align__(16) bf16 Psm[8][32][68];  // per-wave [q][key]
    int blk = blockIdx.x;
    int bh = blk & 63;
    int praw = blk >> 6;               // 0..7
    int jb8 = praw < 4 ? 7 - praw : praw - 4;  // long first; pairs sum nt=36
    int tid = threadIdx.x, w = tid >> 6, lane = tid & 63;
    int lo = lane & 15, qu = lane >> 4;
    int b = bh >> 4, h = bh & 15;
    int qbase = jb8 * 256 + w * 32;
    int nt = 4 * jb8 + 4;
    const bf16* Qb = Q + (size_t)bh * S_ * HD_;
    const bf16* Kb = K + (size_t)bh * S_ * HD_;
    const bf16* Vb = Vt + (size_t)bh * HD_ * S_;

    // Q fragments (A layout: m=lo, k=qu*8+jj, +32*ks)
    bf16x8 qf[2][2];
#pragma unroll
    for (int i = 0; i < 2; i++)
#pragma unroll
        for (int ks = 0; ks < 2; ks++)
            qf[i][ks] = *reinterpret_cast<const bf16x8*>(
                Qb + (size_t)(qbase + i * 16 + lo) * HD_ + ks * 32 + qu * 8);

    bf16x8 onesf;
#pragma unroll
    for (int j = 0; j < 8; j++) onesf[j] = (bf16)1.0f;

    f32x4 zero = {0.f, 0.f, 0.f, 0.f};
    f32x4 o[2][4];
    f32x4 lacc[2];
#pragma unroll
    for (int i = 0; i < 2; i++) {
        lacc[i] = zero;
#pragma unroll
        for (int r = 0; r < 4; r++) o[i][r] = zero;
    }

    int r0 = w * 8;                    // this wave's 8 staging rows (K and V)
    int lrow = lane >> 3, lch = lane & 7;
    int gch = (lch ^ lrow) * 8;        // swizzled global chunk: LDS chunk c of
                                       // row r holds global chunk c ^ (r&7)

    auto stageKV = [&](int t, int buf) {
        int kb = t * 64;
        GLOAD_LDS16(Kb + (size_t)(kb + r0 + lrow) * HD_ + gch, &Ks[buf][r0][0]);
        GLOAD_LDS16(Vb + (size_t)(r0 + lrow) * S_ + kb + gch, &Vs[buf][r0][0]);
    };

    stageKV(0, 0);

    for (int t = 0; t < nt; t++) {
        int cur = t & 1;
        if (t + 1 < nt) {
            stageKV(t + 1, cur ^ 1);
            // retire tile t's 2 loads; leave tile t+1's 2 in flight
            asm volatile("s_waitcnt vmcnt(2)" ::: "memory");
        } else {
            asm volatile("s_waitcnt vmcnt(0)" ::: "memory");
        }
        __builtin_amdgcn_s_barrier();
        asm volatile("" ::: "memory");
        int kb = t * 64;
        if (kb <= qbase + 31) {  // skip fully-masked tiles (keep barriers)
            // ---- K fragments from LDS (swizzle-corrected) ----
            bf16x8 kf[4][2];
#pragma unroll
            for (int kc = 0; kc < 4; kc++)
#pragma unroll
                for (int ks = 0; ks < 2; ks++)
                    kf[kc][ks] = *reinterpret_cast<const bf16x8*>(
                        &Ks[cur][kc * 16 + lo][((ks * 4 + qu) ^ (lo & 7)) * 8]);
            // ---- S^T = K Q^T (swapped): st[kc][i] =
            //      S[key=kb+kc*16+qu*4+r][query=qbase+i*16+lo] ----
            f32x4 st[4][2];
            __builtin_amdgcn_s_setprio(1);
#pragma unroll
            for (int kc = 0; kc < 4; kc++)
#pragma unroll
                for (int i = 0; i < 2; i++) {
                    f32x4 a = __builtin_amdgcn_mfma_f32_16x16x32_bf16(
                        kf[kc][0], qf[i][0], zero, 0, 0, 0);
                    st[kc][i] = __builtin_amdgcn_mfma_f32_16x16x32_bf16(
                        kf[kc][1], qf[i][1], a, 0, 0, 0);
                }
            __builtin_amdgcn_s_setprio(0);
            // ---- mask (diagonal tiles only) + exp2 ----
            if (kb + 63 > qbase) {
#pragma unroll
                for (int kc = 0; kc < 4; kc++) {
                    int key = kb + kc * 16 + qu * 4;
#pragma unroll
                    for (int i = 0; i < 2; i++) {
                        int q = qbase + i * 16 + lo;
#pragma unroll
                        for (int r = 0; r < 4; r++)
                            st[kc][i][r] = (key + r > q) ? -1e30f : st[kc][i][r];
                    }
                }
            }
#pragma unroll
            for (int kc = 0; kc < 4; kc++)
#pragma unroll
                for (int i = 0; i < 2; i++)
#pragma unroll
                    for (int r = 0; r < 4; r++)
                        st[kc][i][r] = EXP2F(st[kc][i][r]);
            // ---- P: 4 consecutive keys per lane -> one b64 write each ----
#pragma unroll
            for (int i = 0; i < 2; i++)
#pragma unroll
                for (int kc = 0; kc < 4; kc++) {
                    bf16x4 pk;
#pragma unroll
                    for (int r = 0; r < 4; r++) pk[r] = (bf16)st[kc][i][r];
                    *reinterpret_cast<bf16x4*>(
                        &Psm[w][i * 16 + lo][kc * 16 + qu * 4]) = pk;
                }
            asm volatile("s_waitcnt lgkmcnt(0)" ::: "memory");
            bf16x8 pa[2][2];
#pragma unroll
            for (int i = 0; i < 2; i++)
#pragma unroll
                for (int ks = 0; ks < 2; ks++)
                    pa[i][ks] = *reinterpret_cast<const bf16x8*>(
                        &Psm[w][i * 16 + lo][ks * 32 + qu * 8]);
            // ---- V fragments (after pack: kf/vfr lifetimes disjoint) ----
            bf16x8 vfr[4][2];
#pragma unroll
            for (int nc = 0; nc < 4; nc++)
#pragma unroll
                for (int ks = 0; ks < 2; ks++)
                    vfr[nc][ks] = *reinterpret_cast<const bf16x8*>(
                        &Vs[cur][nc * 16 + lo][((ks * 4 + qu) ^ (lo & 7)) * 8]);
            // ---- O += P V ; l += P * ones ----
            __builtin_amdgcn_s_setprio(1);
#pragma unroll
            for (int i = 0; i < 2; i++) {
                lacc[i] = __builtin_amdgcn_mfma_f32_16x16x32_bf16(
                    pa[i][0], onesf, lacc[i], 0, 0, 0);
                lacc[i] = __builtin_amdgcn_mfma_f32_16x16x32_bf16(
                    pa[i][1], onesf, lacc[i], 0, 0, 0);
            }
#pragma unroll
            for (int nc = 0; nc < 4; nc++)
#pragma unroll
                for (int i = 0; i < 2; i++) {
                    o[i][nc] = __builtin_amdgcn_mfma_f32_16x16x32_bf16(
                        pa[i][0], vfr[nc][0], o[i][nc], 0, 0, 0);
                    o[i][nc] = __builtin_amdgcn_mfma_f32_16x16x32_bf16(
                        pa[i][1], vfr[nc][1], o[i][nc], 0, 0, 0);
                }
            __builtin_amdgcn_s_setprio(0);
        }
        asm volatile("" ::: "memory");
        __builtin_amdgcn_s_barrier();   // buf reads done before next prefetch
        asm volatile("" ::: "memory");
    }

    // epilogue: Y[b, s, h*64 + d] bf16  (lacc[i][r] = denom for row qu*4+r)
#pragma unroll
    for (int i = 0; i < 2; i++) {
#pragma unroll
        for (int r = 0; r < 4; r++) {
            float inv = RCPF(lacc[i][r]);
            int s = qbase + i * 16 + qu * 4 + r;
#pragma unroll
            for (int nc = 0; nc < 4; nc++) {
                float v = o[i][nc][r] * inv;
                Y[((size_t)(b * S_ + s) * H_ + h) * HD_ + nc * 16 + lo] = (bf16)v;
            }
        }
    }
}

extern "C" void kernel_launch(void* const* d_in, const int* in_sizes, int n_in,
                              void* d_out, int out_size, void* d_ws, size_t ws_size,
                              hipStream_t stream) {
    const float* x      = (const float*)d_in[0];
    const float* W_attn = (const float*)d_in[1];
    const float* b_attn = (const float*)d_in[2];
    const float* W_proj = (const float*)d_in[3];
    const float* b_proj = (const float*)d_in[4];
    float* out = (float*)d_out;

    char* ws = (char*)d_ws;
    size_t off = 0;
    auto alloc = [&](size_t bytes) -> void* {
        void* p = ws + off;
        off += (bytes + 255) & ~(size_t)255;
        return p;
    };
    const size_t MD = (size_t)B_ * S_ * D_;  // 8388608
    bf16* xb  = (bf16*)alloc(MD * 2);
    bf16* wta = (bf16*)alloc((size_t)3 * D_ * D_ * 2);
    bf16* wtp = (bf16*)alloc((size_t)D_ * D_ * 2);
    bf16* Qb  = (bf16*)alloc(MD * 2);
    bf16* Kb  = (bf16*)alloc(MD * 2);
    bf16* Vtb = (bf16*)alloc(MD * 2);  // V written transposed by GEMM1
    bf16* Ya  = (bf16*)alloc(MD * 2);

    k_cvt<<<8192, 256, 0, stream>>>(x, xb, (int)MD);
    k_transpose_cvt<<<dim3(96, 32), 256, 0, stream>>>(W_attn, wta, D_, 3 * D_);
    k_transpose_cvt<<<dim3(32, 32), 256, 0, stream>>>(W_proj, wtp, D_, D_);
    k_gemm<0><<<dim3(24, 64), 512, 0, stream>>>(xb, wta, b_attn, Qb, Kb, Vtb,
                                                B_ * S_, 3 * D_, D_);
    k_attn<<<dim3(512), 512, 0, stream>>>(Qb, Kb, Vtb, Ya);
    k_gemm<1><<<dim3(8, 64), 512, 0, stream>>>(Ya, wtp, b_proj, out, nullptr, nullptr,
                                               B_ * S_, D_, D_);
}

// Round 12
// 233.679 us; speedup vs baseline: 1.0173x; 1.0173x over previous
//
#include <hip/hip_runtime.h>
#include <hip/hip_bf16.h>
#include <math.h>

// CausalSelfAttention: B=4, S=2048, D=1024, H=16, HD=64
// v14: attn reverted to v11 (v13's band pairing destroyed co-residency overlap:
//      (32,4) pairs left CUs half-empty; v11's (32,18) pairs measured best).
//      k_gemm: + bijective XCD-chunked block swizzle l'=(l%8)*(nwg/8)+l/8 --
//      each XCD owns 8 consecutive by-rows so its A-panels (2MB) stay in its
//      private 4MB L2 across all bx neighbors (FETCH was 76.8MB vs 22MB unique).

typedef __bf16 bf16;
typedef __bf16 bf16x8 __attribute__((ext_vector_type(8)));
typedef __bf16 bf16x4 __attribute__((ext_vector_type(4)));
typedef float f32x4 __attribute__((ext_vector_type(4)));

#define B_ 4
#define S_ 2048
#define D_ 1024
#define H_ 16
#define HD_ 64
#define QSCALE 0.1803368801f  /* 0.125 * log2(e) */

#if __has_builtin(__builtin_amdgcn_exp2f)
#define EXP2F(x) __builtin_amdgcn_exp2f(x)
#else
#define EXP2F(x) exp2f(x)
#endif
#if __has_builtin(__builtin_amdgcn_rcpf)
#define RCPF(x) __builtin_amdgcn_rcpf(x)
#else
#define RCPF(x) (1.0f / (x))
#endif

#define GLOAD_LDS16(gptr, lptr)                                              \
    __builtin_amdgcn_global_load_lds(                                        \
        (const __attribute__((address_space(1))) void*)(uintptr_t)(gptr),    \
        (__attribute__((address_space(3))) void*)(uintptr_t)(lptr), 16, 0, 0)

// ---------------- convert fp32 -> bf16 ----------------
__global__ void k_cvt(const float* __restrict__ in, bf16* __restrict__ out, int n) {
    int i = (blockIdx.x * 256 + threadIdx.x) * 4;
    if (i >= n) return;
    float4 v = *reinterpret_cast<const float4*>(in + i);
    bf16x4 o;
    o.x = (bf16)v.x; o.y = (bf16)v.y; o.z = (bf16)v.z; o.w = (bf16)v.w;
    *reinterpret_cast<bf16x4*>(out + i) = o;
}

// ---------------- transpose + convert: W[K][N] -> WT[N][K] bf16 ----------------
__global__ void k_transpose_cvt(const float* __restrict__ W, bf16* __restrict__ WT,
                                int K, int N) {
    __shared__ float t[32][33];
    int n0 = blockIdx.x * 32, k0 = blockIdx.y * 32;
    int tx = threadIdx.x & 31, ty = threadIdx.x >> 5;  // ty in 0..7
#pragma unroll
    for (int j = 0; j < 32; j += 8)
        t[ty + j][tx] = W[(size_t)(k0 + ty + j) * N + n0 + tx];
    __syncthreads();
#pragma unroll
    for (int j = 0; j < 32; j += 8)
        WT[(size_t)(n0 + ty + j) * K + k0 + tx] = (bf16)t[tx][ty + j];
}

// ---------------- bf16 MFMA GEMM v14: C = A[M][K] * BT[N][K]^T ---------------
// 128x128 tile, BK=64, double-buffered, counted vmcnt(4), raw barriers,
// 8 waves (512 thr), wave grid 2x4. XCD-chunked bijective block swizzle
// (requires nwg % 8 == 0; grids are 1536 and 512).
// MODE 0: Q (prescaled) [bh][s][d], K [bh][s][d], V -> Vt [bh][d][s]
// MODE 1: fp32 out[M][N]
template <int MODE>
__global__ __launch_bounds__(512, 4) void k_gemm(
    const bf16* __restrict__ A, const bf16* __restrict__ BT,
    const float* __restrict__ bias,
    void* out0, void* out1, void* out2, int M, int N, int K) {
    __shared__ __align__(16) bf16 Asm[2][128][64];
    __shared__ __align__(16) bf16 Bsm[2][128][64];
    // XCD-chunked swizzle: dispatch-order d lands on XCD d%8; give XCD x the
    // contiguous grid chunk [x*nwg/8, (x+1)*nwg/8)  -> A-panels stay in its L2.
    int nwgx = gridDim.x;
    int nwg = nwgx * gridDim.y;
    int l = blockIdx.y * nwgx + blockIdx.x;
    int cpx = nwg >> 3;
    int ls = (l & 7) * cpx + (l >> 3);
    int bx = ls % nwgx, by = ls / nwgx;
    int mb = by * 128, nb = bx * 128;
    int tid = threadIdx.x;
    int w = tid >> 6, lane = tid & 63, lo = lane & 15, qu = lane >> 4;
    int wm = (w >> 2) * 64, wn = (w & 3) * 32;
    int srow = lane >> 3, sch = lane & 7;
    int gch = (sch ^ srow) * 8;   // swizzled global chunk (bf16 elems)
    int r0 = w * 16;              // this wave's 16 staging rows per matrix

    f32x4 zero = {0.f, 0.f, 0.f, 0.f};
    f32x4 acc[4][2];
#pragma unroll
    for (int i = 0; i < 4; i++)
#pragma unroll
        for (int j = 0; j < 2; j++) acc[i][j] = zero;

    const int nt = K >> 6;  // 16

    auto stage = [&](int t, int buf) {
        int kb = t * 64;
#pragma unroll
        for (int g = 0; g < 2; g++) {
            int row = r0 + g * 8;  // 8-row group; lane covers row+srow
            GLOAD_LDS16(A + (size_t)(mb + row + srow) * K + kb + gch,
                        &Asm[buf][row][0]);
            GLOAD_LDS16(BT + (size_t)(nb + row + srow) * K + kb + gch,
                        &Bsm[buf][row][0]);
        }
    };

    stage(0, 0);

    for (int t = 0; t < nt; t++) {
        int cur = t & 1;
        if (t + 1 < nt) {
            stage(t + 1, cur ^ 1);
            // retire tile t's 4 loads; leave tile t+1's 4 in flight
            asm volatile("s_waitcnt vmcnt(4)" ::: "memory");
        } else {
            asm volatile("s_waitcnt vmcnt(0)" ::: "memory");
        }
        __builtin_amdgcn_s_barrier();
        asm volatile("" ::: "memory");
        bf16x8 af[4][2], bfr[2][2];
#pragma unroll
        for (int tt = 0; tt < 4; tt++)
#pragma unroll
            for (int ks = 0; ks < 2; ks++)
                af[tt][ks] = *reinterpret_cast<const bf16x8*>(
                    &Asm[cur][wm + tt * 16 + lo][((ks * 4 + qu) ^ (lo & 7)) * 8]);
#pragma unroll
        for (int j = 0; j < 2; j++)
#pragma unroll
            for (int ks = 0; ks < 2; ks++)
                bfr[j][ks] = *reinterpret_cast<const bf16x8*>(
                    &Bsm[cur][wn + j * 16 + lo][((ks * 4 + qu) ^ (lo & 7)) * 8]);
        __builtin_amdgcn_s_setprio(1);
#pragma unroll
        for (int i = 0; i < 4; i++)
#pragma unroll
            for (int j = 0; j < 2; j++) {
                acc[i][j] = __builtin_amdgcn_mfma_f32_16x16x32_bf16(
                    af[i][0], bfr[j][0], acc[i][j], 0, 0, 0);
                acc[i][j] = __builtin_amdgcn_mfma_f32_16x16x32_bf16(
                    af[i][1], bfr[j][1], acc[i][j], 0, 0, 0);
            }
        __builtin_amdgcn_s_setprio(0);
        asm volatile("" ::: "memory");
        __builtin_amdgcn_s_barrier();   // buf reads done before next prefetch
        asm volatile("" ::: "memory");
    }

#pragma unroll
    for (int i = 0; i < 4; i++) {
#pragma unroll
        for (int j = 0; j < 2; j++) {
            int col = nb + wn + j * 16 + lo;
            float bv = bias[col];
            float v4v[4];
#pragma unroll
            for (int r = 0; r < 4; r++) v4v[r] = acc[i][j][r] + bv;
            int row0 = mb + wm + i * 16 + qu * 4;
            if (MODE == 0) {
                int b = row0 >> 11, s0 = row0 & 2047;
                int which = col >> 10, rem = col & 1023;
                int h = rem >> 6, d = rem & 63;
                int bh = b * H_ + h;
                if (which == 2) {
                    // V: write transposed Vt[bh][d][s], 4 consecutive s packed
                    bf16x4 pk;
#pragma unroll
                    for (int r = 0; r < 4; r++) pk[r] = (bf16)v4v[r];
                    *reinterpret_cast<bf16x4*>(
                        (bf16*)out2 + ((size_t)bh * HD_ + d) * S_ + s0) = pk;
                } else {
                    bf16* dst = which == 0 ? (bf16*)out0 : (bf16*)out1;
                    float sc = which == 0 ? QSCALE : 1.0f;
#pragma unroll
                    for (int r = 0; r < 4; r++)
                        dst[((size_t)bh * S_ + s0 + r) * HD_ + d] = (bf16)(v4v[r] * sc);
                }
            } else {
#pragma unroll
                for (int r = 0; r < 4; r++)
                    ((float*)out0)[(size_t)(row0 + r) * N + col] = v4v[r];
            }
        }
    }
}

// ---------------- flash attention v11: 8-wave shared-KV paired bands ----------
// grid 512 blocks x 512 thr. Block (bh, p): waves 0-3 = band jb=15-p (rows
// (15-p)*128 + (w&3)*32), waves 4-7 = band jb=p. One shared K/V double-buffer;
// lo band's tiles are a prefix of hi band's. nt = 32-2p; p remapped
// (raw<4 ? raw : 11-raw) so co-resident pairs (blk, blk+256) sum to 50 tiles.
// Swapped QK^T: st = mfma(K,Q) -> lane holds S^T[key=kc*16+qu*4+r][q=lo];
// P packed as bf16x4 (4 consecutive keys) -> 1 ds_write_b64 per (i,kc).
__global__ __launch_bounds__(512, 4) void k_attn(
    const bf16* __restrict__ Q, const bf16* __restrict__ K,
    const bf16* __restrict__ Vt, bf16* __restrict__ Y) {
    __shared__ __align__(16) bf16 Ks[2][64][64];   // [buf][key][d]   (swizzled)
    __shared__ __align__(16) bf16 Vs[2][64][64];   // [buf][d][key]   (swizzled)
    __shared__ __align__(16) bf16 Psm[8][32][68];  // per-wave [q][key]
    int blk = blockIdx.x;
    int bh = blk & 63;
    int praw = blk >> 6;
    int p = praw < 4 ? praw : 11 - praw;   // pair long+short across CU
    int tid = threadIdx.x, w = tid >> 6, lane = tid & 63;
    int lo = lane & 15, qu = lane >> 4;
    int b = bh >> 4, h = bh & 15;
    int band = (w < 4) ? (15 - p) : p;
    int qbase = band * 128 + (w & 3) * 32;
    int nt = 32 - 2 * p;
    const bf16* Qb = Q + (size_t)bh * S_ * HD_;
    const bf16* Kb = K + (size_t)bh * S_ * HD_;
    const bf16* Vb = Vt + (size_t)bh * HD_ * S_;

    // Q fragments (A layout: m=lo, k=qu*8+jj, +32*ks)
    bf16x8 qf[2][2];
#pragma unroll
    for (int i = 0; i < 2; i++)
#pragma unroll
        for (int ks = 0; ks < 2; ks++)
            qf[i][ks] = *reinterpret_cast<const bf16x8*>(
                Qb + (size_t)(qbase + i * 16 + lo) * HD_ + ks * 32 + qu * 8);

    bf16x8 onesf;
#pragma unroll
    for (int j = 0; j < 8; j++) onesf[j] = (bf16)1.0f;

    f32x4 zero = {0.f, 0.f, 0.f, 0.f};
    f32x4 o[2][4];
    f32x4 lacc[2];
#pragma unroll
    for (int i = 0; i < 2; i++) {
        lacc[i] = zero;
#pragma unroll
        for (int r = 0; r < 4; r++) o[i][r] = zero;
    }

    int r0 = w * 8;                    // this wave's 8 staging rows (K and V)
    int lrow = lane >> 3, lch = lane & 7;
    int gch = (lch ^ lrow) * 8;        // swizzled global chunk: LDS chunk c of
                                       // row r holds global chunk c ^ (r&7)

    auto stageKV = [&](int t, int buf) {
        int kb = t * 64;
        GLOAD_LDS16(Kb + (size_t)(kb + r0 + lrow) * HD_ + gch, &Ks[buf][r0][0]);
        GLOAD_LDS16(Vb + (size_t)(r0 + lrow) * S_ + kb + gch, &Vs[buf][r0][0]);
    };

    stageKV(0, 0);

    for (int t = 0; t < nt; t++) {
        int cur = t & 1;
        if (t + 1 < nt) {
            stageKV(t + 1, cur ^ 1);
            // retire tile t's 2 loads; leave tile t+1's 2 in flight
            asm volatile("s_waitcnt vmcnt(2)" ::: "memory");
        } else {
            asm volatile("s_waitcnt vmcnt(0)" ::: "memory");
        }
        __builtin_amdgcn_s_barrier();
        asm volatile("" ::: "memory");
        int kb = t * 64;
        if (kb <= qbase + 31) {  // skip fully-masked tiles (keep barriers)
            // ---- K fragments from LDS (swizzle-corrected) ----
            bf16x8 kf[4][2];
#pragma unroll
            for (int kc = 0; kc < 4; kc++)
#pragma unroll
                for (int ks = 0; ks < 2; ks++)
                    kf[kc][ks] = *reinterpret_cast<const bf16x8*>(
                        &Ks[cur][kc * 16 + lo][((ks * 4 + qu) ^ (lo & 7)) * 8]);
            // ---- S^T = K Q^T (swapped): st[kc][i] =
            //      S[key=kb+kc*16+qu*4+r][query=qbase+i*16+lo] ----
            f32x4 st[4][2];
            __builtin_amdgcn_s_setprio(1);
#pragma unroll
            for (int kc = 0; kc < 4; kc++)
#pragma unroll
                for (int i = 0; i < 2; i++) {
                    f32x4 a = __builtin_amdgcn_mfma_f32_16x16x32_bf16(
                        kf[kc][0], qf[i][0], zero, 0, 0, 0);
                    st[kc][i] = __builtin_amdgcn_mfma_f32_16x16x32_bf16(
                        kf[kc][1], qf[i][1], a, 0, 0, 0);
                }
            __builtin_amdgcn_s_setprio(0);
            // ---- mask (diagonal tiles only) + exp2 ----
            if (kb + 63 > qbase) {
#pragma unroll
                for (int kc = 0; kc < 4; kc++) {
                    int key = kb + kc * 16 + qu * 4;
#pragma unroll
                    for (int i = 0; i < 2; i++) {
                        int q = qbase + i * 16 + lo;
#pragma unroll
                        for (int r = 0; r < 4; r++)
                            st[kc][i][r] = (key + r > q) ? -1e30f : st[kc][i][r];
                    }
                }
            }
#pragma unroll
            for (int kc = 0; kc < 4; kc++)
#pragma unroll
                for (int i = 0; i < 2; i++)
#pragma unroll
                    for (int r = 0; r < 4; r++)
                        st[kc][i][r] = EXP2F(st[kc][i][r]);
            // ---- P: 4 consecutive keys per lane -> one b64 write each ----
#pragma unroll
            for (int i = 0; i < 2; i++)
#pragma unroll
                for (int kc = 0; kc < 4; kc++) {
                    bf16x4 pk;
#pragma unroll
                    for (int r = 0; r < 4; r++) pk[r] = (bf16)st[kc][i][r];
                    *reinterpret_cast<bf16x4*>(
                        &Psm[w][i * 16 + lo][kc * 16 + qu * 4]) = pk;
                }
            asm volatile("s_waitcnt lgkmcnt(0)" ::: "memory");
            bf16x8 pa[2][2];
#pragma unroll
            for (int i = 0; i < 2; i++)
#pragma unroll
                for (int ks = 0; ks < 2; ks++)
                    pa[i][ks] = *reinterpret_cast<const bf16x8*>(
                        &Psm[w][i * 16 + lo][ks * 32 + qu * 8]);
            // ---- V fragments (after pack: kf/vfr lifetimes disjoint) ----
            bf16x8 vfr[4][2];
#pragma unroll
            for (int nc = 0; nc < 4; nc++)
#pragma unroll
                for (int ks = 0; ks < 2; ks++)
                    vfr[nc][ks] = *reinterpret_cast<const bf16x8*>(
                        &Vs[cur][nc * 16 + lo][((ks * 4 + qu) ^ (lo & 7)) * 8]);
            // ---- O += P V ; l += P * ones ----
            __builtin_amdgcn_s_setprio(1);
#pragma unroll
            for (int i = 0; i < 2; i++) {
                lacc[i] = __builtin_amdgcn_mfma_f32_16x16x32_bf16(
                    pa[i][0], onesf, lacc[i], 0, 0, 0);
                lacc[i] = __builtin_amdgcn_mfma_f32_16x16x32_bf16(
                    pa[i][1], onesf, lacc[i], 0, 0, 0);
            }
#pragma unroll
            for (int nc = 0; nc < 4; nc++)
#pragma unroll
                for (int i = 0; i < 2; i++) {
                    o[i][nc] = __builtin_amdgcn_mfma_f32_16x16x32_bf16(
                        pa[i][0], vfr[nc][0], o[i][nc], 0, 0, 0);
                    o[i][nc] = __builtin_amdgcn_mfma_f32_16x16x32_bf16(
                        pa[i][1], vfr[nc][1], o[i][nc], 0, 0, 0);
                }
            __builtin_amdgcn_s_setprio(0);
        }
        asm volatile("" ::: "memory");
        __builtin_amdgcn_s_barrier();   // buf reads done before next prefetch
        asm volatile("" ::: "memory");
    }

    // epilogue: Y[b, s, h*64 + d] bf16  (lacc[i][r] = denom for row qu*4+r)
#pragma unroll
    for (int i = 0; i < 2; i++) {
#pragma unroll
        for (int r = 0; r < 4; r++) {
            float inv = RCPF(lacc[i][r]);
            int s = qbase + i * 16 + qu * 4 + r;
#pragma unroll
            for (int nc = 0; nc < 4; nc++) {
                float v = o[i][nc][r] * inv;
                Y[((size_t)(b * S_ + s) * H_ + h) * HD_ + nc * 16 + lo] = (bf16)v;
            }
        }
    }
}

extern "C" void kernel_launch(void* const* d_in, const int* in_sizes, int n_in,
                              void* d_out, int out_size, void* d_ws, size_t ws_size,
                              hipStream_t stream) {
    const float* x      = (const float*)d_in[0];
    const float* W_attn = (const float*)d_in[1];
    const float* b_attn = (const float*)d_in[2];
    const float* W_proj = (const float*)d_in[3];
    const float* b_proj = (const float*)d_in[4];
    float* out = (float*)d_out;

    char* ws = (char*)d_ws;
    size_t off = 0;
    auto alloc = [&](size_t bytes) -> void* {
        void* p = ws + off;
        off += (bytes + 255) & ~(size_t)255;
        return p;
    };
    const size_t MD = (size_t)B_ * S_ * D_;  // 8388608
    bf16* xb  = (bf16*)alloc(MD * 2);
    bf16* wta = (bf16*)alloc((size_t)3 * D_ * D_ * 2);
    bf16* wtp = (bf16*)alloc((size_t)D_ * D_ * 2);
    bf16* Qb  = (bf16*)alloc(MD * 2);
    bf16* Kb  = (bf16*)alloc(MD * 2);
    bf16* Vtb = (bf16*)alloc(MD * 2);  // V written transposed by GEMM1
    bf16* Ya  = (bf16*)alloc(MD * 2);

    k_cvt<<<8192, 256, 0, stream>>>(x, xb, (int)MD);
    k_transpose_cvt<<<dim3(96, 32), 256, 0, stream>>>(W_attn, wta, D_, 3 * D_);
    k_transpose_cvt<<<dim3(32, 32), 256, 0, stream>>>(W_proj, wtp, D_, D_);
    k_gemm<0><<<dim3(24, 64), 512, 0, stream>>>(xb, wta, b_attn, Qb, Kb, Vtb,
                                                B_ * S_, 3 * D_, D_);
    k_attn<<<dim3(512), 512, 0, stream>>>(Qb, Kb, Vtb, Ya);
    k_gemm<1><<<dim3(8, 64), 512, 0, stream>>>(Ya, wtp, b_proj, out, nullptr, nullptr,
                                               B_ * S_, D_, D_);
}

// Round 13
// 231.827 us; speedup vs baseline: 1.0255x; 1.0080x over previous
//
#include <hip/hip_runtime.h>
#include <hip/hip_bf16.h>
#include <math.h>

// CausalSelfAttention: B=4, S=2048, D=1024, H=16, HD=64
// v15: (a) GEMM swizzle REVERTED (v14 measured FETCH 77->120MB, dur +2us:
//      the workgroup->XCD mapping assumption was wrong; v12 GEMM is the
//      bench-anchored best). (b) attn: 128-row bands split 8 ways (16 q-rows
//      per wave, was 32 over 4 waves of a shared 2-band block): wave w is
//      active until its own 16-row diagonal -> ~93% wave utilization (v11:
//      68%), ~10% less total issued work, same pairing-free long-first
//      dispatch over 1024 blocks. Inner-loop index math = v11 with i=0;
//      Psm -> [8][16][68] (LDS 50176).

typedef __bf16 bf16;
typedef __bf16 bf16x8 __attribute__((ext_vector_type(8)));
typedef __bf16 bf16x4 __attribute__((ext_vector_type(4)));
typedef float f32x4 __attribute__((ext_vector_type(4)));

#define B_ 4
#define S_ 2048
#define D_ 1024
#define H_ 16
#define HD_ 64
#define QSCALE 0.1803368801f  /* 0.125 * log2(e) */

#if __has_builtin(__builtin_amdgcn_exp2f)
#define EXP2F(x) __builtin_amdgcn_exp2f(x)
#else
#define EXP2F(x) exp2f(x)
#endif
#if __has_builtin(__builtin_amdgcn_rcpf)
#define RCPF(x) __builtin_amdgcn_rcpf(x)
#else
#define RCPF(x) (1.0f / (x))
#endif

#define GLOAD_LDS16(gptr, lptr)                                              \
    __builtin_amdgcn_global_load_lds(                                        \
        (const __attribute__((address_space(1))) void*)(uintptr_t)(gptr),    \
        (__attribute__((address_space(3))) void*)(uintptr_t)(lptr), 16, 0, 0)

// ---------------- convert fp32 -> bf16 ----------------
__global__ void k_cvt(const float* __restrict__ in, bf16* __restrict__ out, int n) {
    int i = (blockIdx.x * 256 + threadIdx.x) * 4;
    if (i >= n) return;
    float4 v = *reinterpret_cast<const float4*>(in + i);
    bf16x4 o;
    o.x = (bf16)v.x; o.y = (bf16)v.y; o.z = (bf16)v.z; o.w = (bf16)v.w;
    *reinterpret_cast<bf16x4*>(out + i) = o;
}

// ---------------- transpose + convert: W[K][N] -> WT[N][K] bf16 ----------------
__global__ void k_transpose_cvt(const float* __restrict__ W, bf16* __restrict__ WT,
                                int K, int N) {
    __shared__ float t[32][33];
    int n0 = blockIdx.x * 32, k0 = blockIdx.y * 32;
    int tx = threadIdx.x & 31, ty = threadIdx.x >> 5;  // ty in 0..7
#pragma unroll
    for (int j = 0; j < 32; j += 8)
        t[ty + j][tx] = W[(size_t)(k0 + ty + j) * N + n0 + tx];
    __syncthreads();
#pragma unroll
    for (int j = 0; j < 32; j += 8)
        WT[(size_t)(n0 + ty + j) * K + k0 + tx] = (bf16)t[tx][ty + j];
}

// ---------------- bf16 MFMA GEMM v12: C = A[M][K] * BT[N][K]^T ---------------
// 128x128 tile, BK=64, double-buffered, counted vmcnt(4), raw barriers.
// 8 waves (512 thr), wave grid 2x4: wave w -> rows (w>>2)*64, cols (w&3)*32.
// [128][64] tiles, row-XOR swizzle (chunk c of row r holds global c^(r&7)).
// MODE 0: Q (prescaled) [bh][s][d], K [bh][s][d], V -> Vt [bh][d][s]
// MODE 1: fp32 out[M][N]
template <int MODE>
__global__ __launch_bounds__(512, 4) void k_gemm(
    const bf16* __restrict__ A, const bf16* __restrict__ BT,
    const float* __restrict__ bias,
    void* out0, void* out1, void* out2, int M, int N, int K) {
    __shared__ __align__(16) bf16 Asm[2][128][64];
    __shared__ __align__(16) bf16 Bsm[2][128][64];
    int mb = blockIdx.y * 128, nb = blockIdx.x * 128;
    int tid = threadIdx.x;
    int w = tid >> 6, lane = tid & 63, lo = lane & 15, qu = lane >> 4;
    int wm = (w >> 2) * 64, wn = (w & 3) * 32;
    int srow = lane >> 3, sch = lane & 7;
    int gch = (sch ^ srow) * 8;   // swizzled global chunk (bf16 elems)
    int r0 = w * 16;              // this wave's 16 staging rows per matrix

    f32x4 zero = {0.f, 0.f, 0.f, 0.f};
    f32x4 acc[4][2];
#pragma unroll
    for (int i = 0; i < 4; i++)
#pragma unroll
        for (int j = 0; j < 2; j++) acc[i][j] = zero;

    const int nt = K >> 6;  // 16

    auto stage = [&](int t, int buf) {
        int kb = t * 64;
#pragma unroll
        for (int g = 0; g < 2; g++) {
            int row = r0 + g * 8;  // 8-row group; lane covers row+srow
            GLOAD_LDS16(A + (size_t)(mb + row + srow) * K + kb + gch,
                        &Asm[buf][row][0]);
            GLOAD_LDS16(BT + (size_t)(nb + row + srow) * K + kb + gch,
                        &Bsm[buf][row][0]);
        }
    };

    stage(0, 0);

    for (int t = 0; t < nt; t++) {
        int cur = t & 1;
        if (t + 1 < nt) {
            stage(t + 1, cur ^ 1);
            // retire tile t's 4 loads; leave tile t+1's 4 in flight
            asm volatile("s_waitcnt vmcnt(4)" ::: "memory");
        } else {
            asm volatile("s_waitcnt vmcnt(0)" ::: "memory");
        }
        __builtin_amdgcn_s_barrier();
        asm volatile("" ::: "memory");
        bf16x8 af[4][2], bfr[2][2];
#pragma unroll
        for (int tt = 0; tt < 4; tt++)
#pragma unroll
            for (int ks = 0; ks < 2; ks++)
                af[tt][ks] = *reinterpret_cast<const bf16x8*>(
                    &Asm[cur][wm + tt * 16 + lo][((ks * 4 + qu) ^ (lo & 7)) * 8]);
#pragma unroll
        for (int j = 0; j < 2; j++)
#pragma unroll
            for (int ks = 0; ks < 2; ks++)
                bfr[j][ks] = *reinterpret_cast<const bf16x8*>(
                    &Bsm[cur][wn + j * 16 + lo][((ks * 4 + qu) ^ (lo & 7)) * 8]);
        __builtin_amdgcn_s_setprio(1);
#pragma unroll
        for (int i = 0; i < 4; i++)
#pragma unroll
            for (int j = 0; j < 2; j++) {
                acc[i][j] = __builtin_amdgcn_mfma_f32_16x16x32_bf16(
                    af[i][0], bfr[j][0], acc[i][j], 0, 0, 0);
                acc[i][j] = __builtin_amdgcn_mfma_f32_16x16x32_bf16(
                    af[i][1], bfr[j][1], acc[i][j], 0, 0, 0);
            }
        __builtin_amdgcn_s_setprio(0);
        asm volatile("" ::: "memory");
        __builtin_amdgcn_s_barrier();   // buf reads done before next prefetch
        asm volatile("" ::: "memory");
    }

#pragma unroll
    for (int i = 0; i < 4; i++) {
#pragma unroll
        for (int j = 0; j < 2; j++) {
            int col = nb + wn + j * 16 + lo;
            float bv = bias[col];
            float v4v[4];
#pragma unroll
            for (int r = 0; r < 4; r++) v4v[r] = acc[i][j][r] + bv;
            int row0 = mb + wm + i * 16 + qu * 4;
            if (MODE == 0) {
                int b = row0 >> 11, s0 = row0 & 2047;
                int which = col >> 10, rem = col & 1023;
                int h = rem >> 6, d = rem & 63;
                int bh = b * H_ + h;
                if (which == 2) {
                    // V: write transposed Vt[bh][d][s], 4 consecutive s packed
                    bf16x4 pk;
#pragma unroll
                    for (int r = 0; r < 4; r++) pk[r] = (bf16)v4v[r];
                    *reinterpret_cast<bf16x4*>(
                        (bf16*)out2 + ((size_t)bh * HD_ + d) * S_ + s0) = pk;
                } else {
                    bf16* dst = which == 0 ? (bf16*)out0 : (bf16*)out1;
                    float sc = which == 0 ? QSCALE : 1.0f;
#pragma unroll
                    for (int r = 0; r < 4; r++)
                        dst[((size_t)bh * S_ + s0 + r) * HD_ + d] = (bf16)(v4v[r] * sc);
                }
            } else {
#pragma unroll
                for (int r = 0; r < 4; r++)
                    ((float*)out0)[(size_t)(row0 + r) * N + col] = v4v[r];
            }
        }
    }
}

// ---------------- flash attention v15: 128-row band, 8 waves x 16 rows -------
// grid 1024 blocks x 512 thr. Block (bh, jb): q rows jb*128 .. +127; wave w
// owns rows jb*128 + w*16 .. +15. nt = 2*jb+2; long blocks dispatched first.
// Wave w active until its own 16-row diagonal -> ~93% utilization. K/V staged
// to LDS (pre-swizzled source, linear dest), double-buffered, counted
// vmcnt(2). Swapped QK^T (mfma(K,Q)); P via one b64 LDS write per kc;
// denominator l = P*ones MFMA. Index math = v11 with i=0.
__global__ __launch_bounds__(512, 4) void k_attn(
    const bf16* __restrict__ Q, const bf16* __restrict__ K,
    const bf16* __restrict__ Vt, bf16* __restrict__ Y) {
    __shared__ __align__(16) bf16 Ks[2][64][64];   // [buf][key][d]   (swizzled)
    __shared__ __align__(16) bf16 Vs[2][64][64];   // [buf][d][key]   (swizzled)
    __shared__ __align__(16) bf16 Psm[8][16][68];  // per-wave [q][key]
    int blk = blockIdx.x;
    int bh = blk & 63;
    int jb = 15 - (blk >> 6);          // long blocks dispatched first
    int tid = threadIdx.x, w = tid >> 6, lane = tid & 63;
    int lo = lane & 15, qu = lane >> 4;
    int b = bh >> 4, h = bh & 15;
    int qbase = jb * 128 + w * 16;
    int nt = 2 * jb + 2;
    const bf16* Qb = Q + (size_t)bh * S_ * HD_;
    const bf16* Kb = K + (size_t)bh * S_ * HD_;
    const bf16* Vb = Vt + (size_t)bh * HD_ * S_;

    // Q fragments (A layout: m=lo, k=qu*8+jj, +32*ks)
    bf16x8 qf[2];
#pragma unroll
    for (int ks = 0; ks < 2; ks++)
        qf[ks] = *reinterpret_cast<const bf16x8*>(
            Qb + (size_t)(qbase + lo) * HD_ + ks * 32 + qu * 8);

    bf16x8 onesf;
#pragma unroll
    for (int j = 0; j < 8; j++) onesf[j] = (bf16)1.0f;

    f32x4 zero = {0.f, 0.f, 0.f, 0.f};
    f32x4 o[4];
    f32x4 lacc = zero;
#pragma unroll
    for (int r = 0; r < 4; r++) o[r] = zero;

    int r0 = w * 8;                    // this wave's 8 staging rows (K and V)
    int lrow = lane >> 3, lch = lane & 7;
    int gch = (lch ^ lrow) * 8;        // swizzled global chunk: LDS chunk c of
                                       // row r holds global chunk c ^ (r&7)

    auto stageKV = [&](int t, int buf) {
        int kb = t * 64;
        GLOAD_LDS16(Kb + (size_t)(kb + r0 + lrow) * HD_ + gch, &Ks[buf][r0][0]);
        GLOAD_LDS16(Vb + (size_t)(r0 + lrow) * S_ + kb + gch, &Vs[buf][r0][0]);
    };

    stageKV(0, 0);

    for (int t = 0; t < nt; t++) {
        int cur = t & 1;
        if (t + 1 < nt) {
            stageKV(t + 1, cur ^ 1);
            // retire tile t's 2 loads; leave tile t+1's 2 in flight
            asm volatile("s_waitcnt vmcnt(2)" ::: "memory");
        } else {
            asm volatile("s_waitcnt vmcnt(0)" ::: "memory");
        }
        __builtin_amdgcn_s_barrier();
        asm volatile("" ::: "memory");
        int kb = t * 64;
        if (kb <= qbase + 15) {  // skip fully-masked tiles (keep barriers)
            // ---- K fragments from LDS (swizzle-corrected) ----
            bf16x8 kf[4][2];
#pragma unroll
            for (int kc = 0; kc < 4; kc++)
#pragma unroll
                for (int ks = 0; ks < 2; ks++)
                    kf[kc][ks] = *reinterpret_cast<const bf16x8*>(
                        &Ks[cur][kc * 16 + lo][((ks * 4 + qu) ^ (lo & 7)) * 8]);
            // ---- S^T = K Q^T (swapped): st[kc] =
            //      S[key=kb+kc*16+qu*4+r][query=qbase+lo] ----
            f32x4 st[4];
            __builtin_amdgcn_s_setprio(1);
#pragma unroll
            for (int kc = 0; kc < 4; kc++) {
                f32x4 a = __builtin_amdgcn_mfma_f32_16x16x32_bf16(
                    kf[kc][0], qf[0], zero, 0, 0, 0);
                st[kc] = __builtin_amdgcn_mfma_f32_16x16x32_bf16(
                    kf[kc][1], qf[1], a, 0, 0, 0);
            }
            __builtin_amdgcn_s_setprio(0);
            // ---- mask (diagonal tiles only) + exp2 ----
            if (kb + 63 > qbase) {
#pragma unroll
                for (int kc = 0; kc < 4; kc++) {
                    int key = kb + kc * 16 + qu * 4;
                    int q = qbase + lo;
#pragma unroll
                    for (int r = 0; r < 4; r++)
                        st[kc][r] = (key + r > q) ? -1e30f : st[kc][r];
                }
            }
#pragma unroll
            for (int kc = 0; kc < 4; kc++)
#pragma unroll
                for (int r = 0; r < 4; r++)
                    st[kc][r] = EXP2F(st[kc][r]);
            // ---- P: 4 consecutive keys per lane -> one b64 write each ----
#pragma unroll
            for (int kc = 0; kc < 4; kc++) {
                bf16x4 pk;
#pragma unroll
                for (int r = 0; r < 4; r++) pk[r] = (bf16)st[kc][r];
                *reinterpret_cast<bf16x4*>(
                    &Psm[w][lo][kc * 16 + qu * 4]) = pk;
            }
            asm volatile("s_waitcnt lgkmcnt(0)" ::: "memory");
            bf16x8 pa[2];
#pragma unroll
            for (int ks = 0; ks < 2; ks++)
                pa[ks] = *reinterpret_cast<const bf16x8*>(
                    &Psm[w][lo][ks * 32 + qu * 8]);
            // ---- V fragments (after pack: kf/vfr lifetimes disjoint) ----
            bf16x8 vfr[4][2];
#pragma unroll
            for (int nc = 0; nc < 4; nc++)
#pragma unroll
                for (int ks = 0; ks < 2; ks++)
                    vfr[nc][ks] = *reinterpret_cast<const bf16x8*>(
                        &Vs[cur][nc * 16 + lo][((ks * 4 + qu) ^ (lo & 7)) * 8]);
            // ---- O += P V ; l += P * ones ----
            __builtin_amdgcn_s_setprio(1);
            lacc = __builtin_amdgcn_mfma_f32_16x16x32_bf16(
                pa[0], onesf, lacc, 0, 0, 0);
            lacc = __builtin_amdgcn_mfma_f32_16x16x32_bf16(
                pa[1], onesf, lacc, 0, 0, 0);
#pragma unroll
            for (int nc = 0; nc < 4; nc++) {
                o[nc] = __builtin_amdgcn_mfma_f32_16x16x32_bf16(
                    pa[0], vfr[nc][0], o[nc], 0, 0, 0);
                o[nc] = __builtin_amdgcn_mfma_f32_16x16x32_bf16(
                    pa[1], vfr[nc][1], o[nc], 0, 0, 0);
            }
            __builtin_amdgcn_s_setprio(0);
        }
        asm volatile("" ::: "memory");
        __builtin_amdgcn_s_barrier();   // buf reads done before next prefetch
        asm volatile("" ::: "memory");
    }

    // epilogue: Y[b, s, h*64 + d] bf16  (lacc[r] = denom for row qu*4+r)
#pragma unroll
    for (int r = 0; r < 4; r++) {
        float inv = RCPF(lacc[r]);
        int s = qbase + qu * 4 + r;
#pragma unroll
        for (int nc = 0; nc < 4; nc++) {
            float v = o[nc][r] * inv;
            Y[((size_t)(b * S_ + s) * H_ + h) * HD_ + nc * 16 + lo] = (bf16)v;
        }
    }
}

extern "C" void kernel_launch(void* const* d_in, const int* in_sizes, int n_in,
                              void* d_out, int out_size, void* d_ws, size_t ws_size,
                              hipStream_t stream) {
    const float* x      = (const float*)d_in[0];
    const float* W_attn = (const float*)d_in[1];
    const float* b_attn = (const float*)d_in[2];
    const float* W_proj = (const float*)d_in[3];
    const float* b_proj = (const float*)d_in[4];
    float* out = (float*)d_out;

    char* ws = (char*)d_ws;
    size_t off = 0;
    auto alloc = [&](size_t bytes) -> void* {
        void* p = ws + off;
        off += (bytes + 255) & ~(size_t)255;
        return p;
    };
    const size_t MD = (size_t)B_ * S_ * D_;  // 8388608
    bf16* xb  = (bf16*)alloc(MD * 2);
    bf16* wta = (bf16*)alloc((size_t)3 * D_ * D_ * 2);
    bf16* wtp = (bf16*)alloc((size_t)D_ * D_ * 2);
    bf16* Qb  = (bf16*)alloc(MD * 2);
    bf16* Kb  = (bf16*)alloc(MD * 2);
    bf16* Vtb = (bf16*)alloc(MD * 2);  // V written transposed by GEMM1
    bf16* Ya  = (bf16*)alloc(MD * 2);

    k_cvt<<<8192, 256, 0, stream>>>(x, xb, (int)MD);
    k_transpose_cvt<<<dim3(96, 32), 256, 0, stream>>>(W_attn, wta, D_, 3 * D_);
    k_transpose_cvt<<<dim3(32, 32), 256, 0, stream>>>(W_proj, wtp, D_, D_);
    k_gemm<0><<<dim3(24, 64), 512, 0, stream>>>(xb, wta, b_attn, Qb, Kb, Vtb,
                                                B_ * S_, 3 * D_, D_);
    k_attn<<<dim3(1024), 512, 0, stream>>>(Qb, Kb, Vtb, Ya);
    k_gemm<1><<<dim3(8, 64), 512, 0, stream>>>(Ya, wtp, b_proj, out, nullptr, nullptr,
                                               B_ * S_, D_, D_);
}

// Round 14
// 223.743 us; speedup vs baseline: 1.0625x; 1.0361x over previous
//
#include <hip/hip_runtime.h>
#include <hip/hip_bf16.h>
#include <math.h>

// CausalSelfAttention: B=4, S=2048, D=1024, H=16, HD=64
// v16: attn reverted to v11 (bench-anchored best; v13/v15 decomposition
//      variants both regressed). Both k_gemm (v12 decomposition) and k_attn
//      converted to SINGLE-barrier double-buffering:
//        { vmcnt(0); s_barrier; stage(t+1 -> buf^1); compute(buf) }
//      WAR on buf^1 is safe: its last readers (iter t-1) retired all ds_reads
//      before reaching barrier t (MFMA data-dependence); stage issues after.
//      RAW on buf: each wave vmcnt(0)'s its own tile-t DMAs (issued a full
//      compute phase earlier -> latency hidden) before the barrier. Removes
//      one convoy point per tile-iteration from both hot kernels.

typedef __bf16 bf16;
typedef __bf16 bf16x8 __attribute__((ext_vector_type(8)));
typedef __bf16 bf16x4 __attribute__((ext_vector_type(4)));
typedef float f32x4 __attribute__((ext_vector_type(4)));

#define B_ 4
#define S_ 2048
#define D_ 1024
#define H_ 16
#define HD_ 64
#define QSCALE 0.1803368801f  /* 0.125 * log2(e) */

#if __has_builtin(__builtin_amdgcn_exp2f)
#define EXP2F(x) __builtin_amdgcn_exp2f(x)
#else
#define EXP2F(x) exp2f(x)
#endif
#if __has_builtin(__builtin_amdgcn_rcpf)
#define RCPF(x) __builtin_amdgcn_rcpf(x)
#else
#define RCPF(x) (1.0f / (x))
#endif

#define GLOAD_LDS16(gptr, lptr)                                              \
    __builtin_amdgcn_global_load_lds(                                        \
        (const __attribute__((address_space(1))) void*)(uintptr_t)(gptr),    \
        (__attribute__((address_space(3))) void*)(uintptr_t)(lptr), 16, 0, 0)

// ---------------- convert fp32 -> bf16 ----------------
__global__ void k_cvt(const float* __restrict__ in, bf16* __restrict__ out, int n) {
    int i = (blockIdx.x * 256 + threadIdx.x) * 4;
    if (i >= n) return;
    float4 v = *reinterpret_cast<const float4*>(in + i);
    bf16x4 o;
    o.x = (bf16)v.x; o.y = (bf16)v.y; o.z = (bf16)v.z; o.w = (bf16)v.w;
    *reinterpret_cast<bf16x4*>(out + i) = o;
}

// ---------------- transpose + convert: W[K][N] -> WT[N][K] bf16 ----------------
__global__ void k_transpose_cvt(const float* __restrict__ W, bf16* __restrict__ WT,
                                int K, int N) {
    __shared__ float t[32][33];
    int n0 = blockIdx.x * 32, k0 = blockIdx.y * 32;
    int tx = threadIdx.x & 31, ty = threadIdx.x >> 5;  // ty in 0..7
#pragma unroll
    for (int j = 0; j < 32; j += 8)
        t[ty + j][tx] = W[(size_t)(k0 + ty + j) * N + n0 + tx];
    __syncthreads();
#pragma unroll
    for (int j = 0; j < 32; j += 8)
        WT[(size_t)(n0 + ty + j) * K + k0 + tx] = (bf16)t[tx][ty + j];
}

// ---------------- bf16 MFMA GEMM v16: C = A[M][K] * BT[N][K]^T ---------------
// 128x128 tile, BK=64, double-buffered, SINGLE barrier/iter, 8 waves (512 thr),
// wave grid 2x4. [128][64] tiles, row-XOR swizzle (chunk c of row r holds
// global c^(r&7)).
// MODE 0: Q (prescaled) [bh][s][d], K [bh][s][d], V -> Vt [bh][d][s]
// MODE 1: fp32 out[M][N]
template <int MODE>
__global__ __launch_bounds__(512, 4) void k_gemm(
    const bf16* __restrict__ A, const bf16* __restrict__ BT,
    const float* __restrict__ bias,
    void* out0, void* out1, void* out2, int M, int N, int K) {
    __shared__ __align__(16) bf16 Asm[2][128][64];
    __shared__ __align__(16) bf16 Bsm[2][128][64];
    int mb = blockIdx.y * 128, nb = blockIdx.x * 128;
    int tid = threadIdx.x;
    int w = tid >> 6, lane = tid & 63, lo = lane & 15, qu = lane >> 4;
    int wm = (w >> 2) * 64, wn = (w & 3) * 32;
    int srow = lane >> 3, sch = lane & 7;
    int gch = (sch ^ srow) * 8;   // swizzled global chunk (bf16 elems)
    int r0 = w * 16;              // this wave's 16 staging rows per matrix

    f32x4 zero = {0.f, 0.f, 0.f, 0.f};
    f32x4 acc[4][2];
#pragma unroll
    for (int i = 0; i < 4; i++)
#pragma unroll
        for (int j = 0; j < 2; j++) acc[i][j] = zero;

    const int nt = K >> 6;  // 16

    auto stage = [&](int t, int buf) {
        int kb = t * 64;
#pragma unroll
        for (int g = 0; g < 2; g++) {
            int row = r0 + g * 8;  // 8-row group; lane covers row+srow
            GLOAD_LDS16(A + (size_t)(mb + row + srow) * K + kb + gch,
                        &Asm[buf][row][0]);
            GLOAD_LDS16(BT + (size_t)(nb + row + srow) * K + kb + gch,
                        &Bsm[buf][row][0]);
        }
    };

    stage(0, 0);

    for (int t = 0; t < nt; t++) {
        int cur = t & 1;
        // my tile-t DMAs were issued a full compute phase ago -> cheap drain
        asm volatile("s_waitcnt vmcnt(0)" ::: "memory");
        __builtin_amdgcn_s_barrier();   // publishes tile t; frees buf^1
        asm volatile("" ::: "memory");
        if (t + 1 < nt) stage(t + 1, cur ^ 1);
        bf16x8 af[4][2], bfr[2][2];
#pragma unroll
        for (int tt = 0; tt < 4; tt++)
#pragma unroll
            for (int ks = 0; ks < 2; ks++)
                af[tt][ks] = *reinterpret_cast<const bf16x8*>(
                    &Asm[cur][wm + tt * 16 + lo][((ks * 4 + qu) ^ (lo & 7)) * 8]);
#pragma unroll
        for (int j = 0; j < 2; j++)
#pragma unroll
            for (int ks = 0; ks < 2; ks++)
                bfr[j][ks] = *reinterpret_cast<const bf16x8*>(
                    &Bsm[cur][wn + j * 16 + lo][((ks * 4 + qu) ^ (lo & 7)) * 8]);
        __builtin_amdgcn_s_setprio(1);
#pragma unroll
        for (int i = 0; i < 4; i++)
#pragma unroll
            for (int j = 0; j < 2; j++) {
                acc[i][j] = __builtin_amdgcn_mfma_f32_16x16x32_bf16(
                    af[i][0], bfr[j][0], acc[i][j], 0, 0, 0);
                acc[i][j] = __builtin_amdgcn_mfma_f32_16x16x32_bf16(
                    af[i][1], bfr[j][1], acc[i][j], 0, 0, 0);
            }
        __builtin_amdgcn_s_setprio(0);
        asm volatile("" ::: "memory");
    }

#pragma unroll
    for (int i = 0; i < 4; i++) {
#pragma unroll
        for (int j = 0; j < 2; j++) {
            int col = nb + wn + j * 16 + lo;
            float bv = bias[col];
            float v4v[4];
#pragma unroll
            for (int r = 0; r < 4; r++) v4v[r] = acc[i][j][r] + bv;
            int row0 = mb + wm + i * 16 + qu * 4;
            if (MODE == 0) {
                int b = row0 >> 11, s0 = row0 & 2047;
                int which = col >> 10, rem = col & 1023;
                int h = rem >> 6, d = rem & 63;
                int bh = b * H_ + h;
                if (which == 2) {
                    // V: write transposed Vt[bh][d][s], 4 consecutive s packed
                    bf16x4 pk;
#pragma unroll
                    for (int r = 0; r < 4; r++) pk[r] = (bf16)v4v[r];
                    *reinterpret_cast<bf16x4*>(
                        (bf16*)out2 + ((size_t)bh * HD_ + d) * S_ + s0) = pk;
                } else {
                    bf16* dst = which == 0 ? (bf16*)out0 : (bf16*)out1;
                    float sc = which == 0 ? QSCALE : 1.0f;
#pragma unroll
                    for (int r = 0; r < 4; r++)
                        dst[((size_t)bh * S_ + s0 + r) * HD_ + d] = (bf16)(v4v[r] * sc);
                }
            } else {
#pragma unroll
                for (int r = 0; r < 4; r++)
                    ((float*)out0)[(size_t)(row0 + r) * N + col] = v4v[r];
            }
        }
    }
}

// ---------------- flash attention v16: v11 structure, single barrier ---------
// grid 512 blocks x 512 thr. Block (bh, p): waves 0-3 = band jb=15-p (rows
// (15-p)*128 + (w&3)*32), waves 4-7 = band jb=p. One shared K/V double-buffer;
// nt = 32-2p; p remapped (raw<4 ? raw : 11-raw) so co-resident pairs
// (blk, blk+256) sum to 50 tiles. Swapped QK^T (mfma(K,Q)); P via b64 LDS
// writes; denominator l = P*ones MFMA. Single barrier per tile-iteration.
__global__ __launch_bounds__(512, 4) void k_attn(
    const bf16* __restrict__ Q, const bf16* __restrict__ K,
    const bf16* __restrict__ Vt, bf16* __restrict__ Y) {
    __shared__ __align__(16) bf16 Ks[2][64][64];   // [buf][key][d]   (swizzled)
    __shared__ __align__(16) bf16 Vs[2][64][64];   // [buf][d][key]   (swizzled)
    __shared__ __align__(16) bf16 Psm[8][32][68];  // per-wave [q][key]
    int blk = blockIdx.x;
    int bh = blk & 63;
    int praw = blk >> 6;
    int p = praw < 4 ? praw : 11 - praw;   // pair long+short across CU
    int tid = threadIdx.x, w = tid >> 6, lane = tid & 63;
    int lo = lane & 15, qu = lane >> 4;
    int b = bh >> 4, h = bh & 15;
    int band = (w < 4) ? (15 - p) : p;
    int qbase = band * 128 + (w & 3) * 32;
    int nt = 32 - 2 * p;
    const bf16* Qb = Q + (size_t)bh * S_ * HD_;
    const bf16* Kb = K + (size_t)bh * S_ * HD_;
    const bf16* Vb = Vt + (size_t)bh * HD_ * S_;

    // Q fragments (A layout: m=lo, k=qu*8+jj, +32*ks)
    bf16x8 qf[2][2];
#pragma unroll
    for (int i = 0; i < 2; i++)
#pragma unroll
        for (int ks = 0; ks < 2; ks++)
            qf[i][ks] = *reinterpret_cast<const bf16x8*>(
                Qb + (size_t)(qbase + i * 16 + lo) * HD_ + ks * 32 + qu * 8);

    bf16x8 onesf;
#pragma unroll
    for (int j = 0; j < 8; j++) onesf[j] = (bf16)1.0f;

    f32x4 zero = {0.f, 0.f, 0.f, 0.f};
    f32x4 o[2][4];
    f32x4 lacc[2];
#pragma unroll
    for (int i = 0; i < 2; i++) {
        lacc[i] = zero;
#pragma unroll
        for (int r = 0; r < 4; r++) o[i][r] = zero;
    }

    int r0 = w * 8;                    // this wave's 8 staging rows (K and V)
    int lrow = lane >> 3, lch = lane & 7;
    int gch = (lch ^ lrow) * 8;        // swizzled global chunk: LDS chunk c of
                                       // row r holds global chunk c ^ (r&7)

    auto stageKV = [&](int t, int buf) {
        int kb = t * 64;
        GLOAD_LDS16(Kb + (size_t)(kb + r0 + lrow) * HD_ + gch, &Ks[buf][r0][0]);
        GLOAD_LDS16(Vb + (size_t)(r0 + lrow) * S_ + kb + gch, &Vs[buf][r0][0]);
    };

    stageKV(0, 0);

    for (int t = 0; t < nt; t++) {
        int cur = t & 1;
        // my tile-t DMAs were issued a full compute phase ago -> cheap drain
        asm volatile("s_waitcnt vmcnt(0)" ::: "memory");
        __builtin_amdgcn_s_barrier();   // publishes tile t; frees buf^1
        asm volatile("" ::: "memory");
        if (t + 1 < nt) stageKV(t + 1, cur ^ 1);
        int kb = t * 64;
        if (kb <= qbase + 31) {  // skip fully-masked tiles (barrier count uniform)
            // ---- K fragments from LDS (swizzle-corrected) ----
            bf16x8 kf[4][2];
#pragma unroll
            for (int kc = 0; kc < 4; kc++)
#pragma unroll
                for (int ks = 0; ks < 2; ks++)
                    kf[kc][ks] = *reinterpret_cast<const bf16x8*>(
                        &Ks[cur][kc * 16 + lo][((ks * 4 + qu) ^ (lo & 7)) * 8]);
            // ---- S^T = K Q^T (swapped): st[kc][i] =
            //      S[key=kb+kc*16+qu*4+r][query=qbase+i*16+lo] ----
            f32x4 st[4][2];
            __builtin_amdgcn_s_setprio(1);
#pragma unroll
            for (int kc = 0; kc < 4; kc++)
#pragma unroll
                for (int i = 0; i < 2; i++) {
                    f32x4 a = __builtin_amdgcn_mfma_f32_16x16x32_bf16(
                        kf[kc][0], qf[i][0], zero, 0, 0, 0);
                    st[kc][i] = __builtin_amdgcn_mfma_f32_16x16x32_bf16(
                        kf[kc][1], qf[i][1], a, 0, 0, 0);
                }
            __builtin_amdgcn_s_setprio(0);
            // ---- mask (diagonal tiles only) + exp2 ----
            if (kb + 63 > qbase) {
#pragma unroll
                for (int kc = 0; kc < 4; kc++) {
                    int key = kb + kc * 16 + qu * 4;
#pragma unroll
                    for (int i = 0; i < 2; i++) {
                        int q = qbase + i * 16 + lo;
#pragma unroll
                        for (int r = 0; r < 4; r++)
                            st[kc][i][r] = (key + r > q) ? -1e30f : st[kc][i][r];
                    }
                }
            }
#pragma unroll
            for (int kc = 0; kc < 4; kc++)
#pragma unroll
                for (int i = 0; i < 2; i++)
#pragma unroll
                    for (int r = 0; r < 4; r++)
                        st[kc][i][r] = EXP2F(st[kc][i][r]);
            // ---- P: 4 consecutive keys per lane -> one b64 write each ----
#pragma unroll
            for (int i = 0; i < 2; i++)
#pragma unroll
                for (int kc = 0; kc < 4; kc++) {
                    bf16x4 pk;
#pragma unroll
                    for (int r = 0; r < 4; r++) pk[r] = (bf16)st[kc][i][r];
                    *reinterpret_cast<bf16x4*>(
                        &Psm[w][i * 16 + lo][kc * 16 + qu * 4]) = pk;
                }
            asm volatile("s_waitcnt lgkmcnt(0)" ::: "memory");
            bf16x8 pa[2][2];
#pragma unroll
            for (int i = 0; i < 2; i++)
#pragma unroll
                for (int ks = 0; ks < 2; ks++)
                    pa[i][ks] = *reinterpret_cast<const bf16x8*>(
                        &Psm[w][i * 16 + lo][ks * 32 + qu * 8]);
            // ---- V fragments (after pack: kf/vfr lifetimes disjoint) ----
            bf16x8 vfr[4][2];
#pragma unroll
            for (int nc = 0; nc < 4; nc++)
#pragma unroll
                for (int ks = 0; ks < 2; ks++)
                    vfr[nc][ks] = *reinterpret_cast<const bf16x8*>(
                        &Vs[cur][nc * 16 + lo][((ks * 4 + qu) ^ (lo & 7)) * 8]);
            // ---- O += P V ; l += P * ones ----
            __builtin_amdgcn_s_setprio(1);
#pragma unroll
            for (int i = 0; i < 2; i++) {
                lacc[i] = __builtin_amdgcn_mfma_f32_16x16x32_bf16(
                    pa[i][0], onesf, lacc[i], 0, 0, 0);
                lacc[i] = __builtin_amdgcn_mfma_f32_16x16x32_bf16(
                    pa[i][1], onesf, lacc[i], 0, 0, 0);
            }
#pragma unroll
            for (int nc = 0; nc < 4; nc++)
#pragma unroll
                for (int i = 0; i < 2; i++) {
                    o[i][nc] = __builtin_amdgcn_mfma_f32_16x16x32_bf16(
                        pa[i][0], vfr[nc][0], o[i][nc], 0, 0, 0);
                    o[i][nc] = __builtin_amdgcn_mfma_f32_16x16x32_bf16(
                        pa[i][1], vfr[nc][1], o[i][nc], 0, 0, 0);
                }
            __builtin_amdgcn_s_setprio(0);
        }
        asm volatile("" ::: "memory");
    }

    // epilogue: Y[b, s, h*64 + d] bf16  (lacc[i][r] = denom for row qu*4+r)
#pragma unroll
    for (int i = 0; i < 2; i++) {
#pragma unroll
        for (int r = 0; r < 4; r++) {
            float inv = RCPF(lacc[i][r]);
            int s = qbase + i * 16 + qu * 4 + r;
#pragma unroll
            for (int nc = 0; nc < 4; nc++) {
                float v = o[i][nc][r] * inv;
                Y[((size_t)(b * S_ + s) * H_ + h) * HD_ + nc * 16 + lo] = (bf16)v;
            }
        }
    }
}

extern "C" void kernel_launch(void* const* d_in, const int* in_sizes, int n_in,
                              void* d_out, int out_size, void* d_ws, size_t ws_size,
                              hipStream_t stream) {
    const float* x      = (const float*)d_in[0];
    const float* W_attn = (const float*)d_in[1];
    const float* b_attn = (const float*)d_in[2];
    const float* W_proj = (const float*)d_in[3];
    const float* b_proj = (const float*)d_in[4];
    float* out = (float*)d_out;

    char* ws = (char*)d_ws;
    size_t off = 0;
    auto alloc = [&](size_t bytes) -> void* {
        void* p = ws + off;
        off += (bytes + 255) & ~(size_t)255;
        return p;
    };
    const size_t MD = (size_t)B_ * S_ * D_;  // 8388608
    bf16* xb  = (bf16*)alloc(MD * 2);
    bf16* wta = (bf16*)alloc((size_t)3 * D_ * D_ * 2);
    bf16* wtp = (bf16*)alloc((size_t)D_ * D_ * 2);
    bf16* Qb  = (bf16*)alloc(MD * 2);
    bf16* Kb  = (bf16*)alloc(MD * 2);
    bf16* Vtb = (bf16*)alloc(MD * 2);  // V written transposed by GEMM1
    bf16* Ya  = (bf16*)alloc(MD * 2);

    k_cvt<<<8192, 256, 0, stream>>>(x, xb, (int)MD);
    k_transpose_cvt<<<dim3(96, 32), 256, 0, stream>>>(W_attn, wta, D_, 3 * D_);
    k_transpose_cvt<<<dim3(32, 32), 256, 0, stream>>>(W_proj, wtp, D_, D_);
    k_gemm<0><<<dim3(24, 64), 512, 0, stream>>>(xb, wta, b_attn, Qb, Kb, Vtb,
                                                B_ * S_, 3 * D_, D_);
    k_attn<<<dim3(512), 512, 0, stream>>>(Qb, Kb, Vtb, Ya);
    k_gemm<1><<<dim3(8, 64), 512, 0, stream>>>(Ya, wtp, b_proj, out, nullptr, nullptr,
                                               B_ * S_, D_, D_);
}